// Round 1
// baseline (36038.986 us; speedup 1.0000x reference)
//
#include <hip/hip_runtime.h>
#include <math.h>

// Problem constants (Qwen3-MoE tiny config)
#define BB    2
#define SS    1024
#define TT    2048          // B*S tokens
#define DD    1024          // model dim
#define HH    16            // q heads
#define KVH   4             // kv heads
#define HDIM  64            // head dim
#define LL    4             // layers
#define EE    8             // experts
#define FF    1024          // ffn dim
#define VV    32000         // vocab
#define EPSF  1e-6f

// ---------------------------------------------------------------------------
// embedding gather: x[t,:] = tok_emb[token_ids[t],:]
__global__ void k_embed(const int* __restrict__ tok, const float* __restrict__ emb,
                        float* __restrict__ x) {
    int t = blockIdx.x;
    int id = tok[t];
    const float* src = emb + (size_t)id * DD;
    float* dst = x + (size_t)t * DD;
    for (int i = threadIdx.x; i < DD; i += blockDim.x) dst[i] = src[i];
}

// ---------------------------------------------------------------------------
// RMSNorm over D=1024, one block per row
__global__ void k_rmsnorm(const float* __restrict__ x, const float* __restrict__ w,
                          float* __restrict__ out) {
    int t = blockIdx.x;
    const float* row = x + (size_t)t * DD;
    float ss = 0.f;
    for (int i = threadIdx.x; i < DD; i += blockDim.x) { float v = row[i]; ss += v * v; }
    __shared__ float red[4];
    for (int o = 32; o > 0; o >>= 1) ss += __shfl_down(ss, o, 64);
    int lane = threadIdx.x & 63, wid = threadIdx.x >> 6;
    if (lane == 0) red[wid] = ss;
    __syncthreads();
    float tot = red[0] + red[1] + red[2] + red[3];
    float r = rsqrtf(tot / (float)DD + EPSF);
    float* o_ = out + (size_t)t * DD;
    for (int i = threadIdx.x; i < DD; i += blockDim.x) o_[i] = row[i] * r * w[i];
}

// ---------------------------------------------------------------------------
// fp32 tiled GEMM: C[M,N] = A[M,K] @ B[K,N]  (row-major)
// 16x16 threads, 4x4 per thread -> 64x64 tile. Optional fused epilogue:
//   accum=0: C = acc*s      accum=1: C += acc*s     s = rowScale ? rowScale[m*rsStride] : 1
__global__ void k_gemm_nn(const float* __restrict__ A, const float* __restrict__ B,
                          float* __restrict__ C, int M, int N, int K,
                          const float* __restrict__ rowScale, int rsStride, int accum) {
    __shared__ float As[64][17];
    __shared__ float Bs[16][65];
    int tx = threadIdx.x, ty = threadIdx.y;
    int tid = ty * 16 + tx;
    int row0 = blockIdx.y * 64;
    int col0 = blockIdx.x * 64;
    float acc[4][4] = {};
    for (int k0 = 0; k0 < K; k0 += 16) {
#pragma unroll
        for (int i = 0; i < 4; i++) {
            int idx = tid + i * 256;
            int r = idx >> 4, c = idx & 15;
            int gr = row0 + r, gc = k0 + c;
            As[r][c] = (gr < M && gc < K) ? A[(size_t)gr * K + gc] : 0.f;
        }
#pragma unroll
        for (int i = 0; i < 4; i++) {
            int idx = tid + i * 256;
            int r = idx >> 6, c = idx & 63;
            int gr = k0 + r, gc = col0 + c;
            Bs[r][c] = (gr < K && gc < N) ? B[(size_t)gr * N + gc] : 0.f;
        }
        __syncthreads();
#pragma unroll
        for (int kk = 0; kk < 16; kk++) {
            float a[4], b[4];
#pragma unroll
            for (int i = 0; i < 4; i++) a[i] = As[ty + 16 * i][kk];
#pragma unroll
            for (int j = 0; j < 4; j++) b[j] = Bs[kk][tx + 16 * j];
#pragma unroll
            for (int i = 0; i < 4; i++)
#pragma unroll
                for (int j = 0; j < 4; j++)
                    acc[i][j] = fmaf(a[i], b[j], acc[i][j]);
        }
        __syncthreads();
    }
#pragma unroll
    for (int i = 0; i < 4; i++) {
        int gr = row0 + ty + 16 * i;
        if (gr >= M) continue;
        float s = rowScale ? rowScale[(size_t)gr * rsStride] : 1.f;
#pragma unroll
        for (int j = 0; j < 4; j++) {
            int gc = col0 + tx + 16 * j;
            if (gc >= N) continue;
            size_t o = (size_t)gr * N + gc;
            float v = acc[i][j] * s;
            if (accum) C[o] += v; else C[o] = v;
        }
    }
}

// ---------------------------------------------------------------------------
// fp32 tiled GEMM-NT: C[M,N] = A[M,K] @ B[N,K]^T   (both row-major, K contiguous)
__global__ void k_gemm_nt(const float* __restrict__ A, const float* __restrict__ B,
                          float* __restrict__ C, int M, int N, int K) {
    __shared__ float As[64][17];
    __shared__ float Bs[16][65];
    int tx = threadIdx.x, ty = threadIdx.y;
    int tid = ty * 16 + tx;
    int row0 = blockIdx.y * 64;
    int col0 = blockIdx.x * 64;
    float acc[4][4] = {};
    for (int k0 = 0; k0 < K; k0 += 16) {
#pragma unroll
        for (int i = 0; i < 4; i++) {
            int idx = tid + i * 256;
            int r = idx >> 4, c = idx & 15;
            int gr = row0 + r, gc = k0 + c;
            As[r][c] = (gr < M && gc < K) ? A[(size_t)gr * K + gc] : 0.f;
        }
#pragma unroll
        for (int i = 0; i < 4; i++) {
            int idx = tid + i * 256;
            int r = idx & 15, c = idx >> 4;          // r = k offset, c = n offset
            int gn = col0 + c, gk = k0 + r;
            Bs[r][c] = (gn < N && gk < K) ? B[(size_t)gn * K + gk] : 0.f;
        }
        __syncthreads();
#pragma unroll
        for (int kk = 0; kk < 16; kk++) {
            float a[4], b[4];
#pragma unroll
            for (int i = 0; i < 4; i++) a[i] = As[ty + 16 * i][kk];
#pragma unroll
            for (int j = 0; j < 4; j++) b[j] = Bs[kk][tx + 16 * j];
#pragma unroll
            for (int i = 0; i < 4; i++)
#pragma unroll
                for (int j = 0; j < 4; j++)
                    acc[i][j] = fmaf(a[i], b[j], acc[i][j]);
        }
        __syncthreads();
    }
#pragma unroll
    for (int i = 0; i < 4; i++) {
        int gr = row0 + ty + 16 * i;
        if (gr >= M) continue;
#pragma unroll
        for (int j = 0; j < 4; j++) {
            int gc = col0 + tx + 16 * j;
            if (gc >= N) continue;
            C[(size_t)gr * N + gc] = acc[i][j];
        }
    }
}

// ---------------------------------------------------------------------------
// per-head RMSNorm (over 64 dims) + RoPE. One 64-lane wave per (token, head).
// nheads = HH for q, KVH for k.
__global__ void k_qknorm_rope(float* __restrict__ q, const float* __restrict__ nw,
                              const int* __restrict__ pos_ids, int nheads) {
    int g = blockIdx.x * 4 + (threadIdx.x >> 6);   // (t*nheads + head)
    int lane = threadIdx.x & 63;
    int t = g / nheads, head = g % nheads;
    size_t base = (size_t)t * nheads * HDIM + (size_t)head * HDIM;
    float v = q[base + lane];
    float ss = v * v;
    for (int o = 32; o > 0; o >>= 1) ss += __shfl_xor(ss, o, 64);
    float r = rsqrtf(ss / (float)HDIM + EPSF);
    v = v * r * nw[lane];
    // RoPE
    int pos = pos_ids[t];
    int i = lane & 31;
    float freq = powf(1000000.0f, -(float)i / 32.0f);
    float ang = (float)pos * freq;
    float c = cosf(ang), s = sinf(ang);
    float partner = __shfl_xor(v, 32, 64);
    float outv = (lane < 32) ? (v * c - partner * s) : (v * c + partner * s);
    q[base + lane] = outv;
}

// ---------------------------------------------------------------------------
// causal attention, one block per (query position, b*H+h). Streaming softmax
// over the already-materialized score row in LDS.
__global__ void k_attn(const float* __restrict__ q, const float* __restrict__ k,
                       const float* __restrict__ v, float* __restrict__ o) {
    int s = blockIdx.x;
    int bh = blockIdx.y;
    int b = bh / HH, h = bh % HH;
    int kvh = h >> 2;                      // GQA: 4 q heads per kv head
    int t = b * SS + s;
    __shared__ float qs[HDIM];
    __shared__ float sc[SS];
    __shared__ float redm[4];
    __shared__ float reds[4];
    __shared__ float part[4][HDIM];
    int tid = threadIdx.x;
    int lane = tid & 63, wid = tid >> 6;
    if (tid < HDIM) qs[tid] = q[(size_t)t * HH * HDIM + h * HDIM + tid];
    __syncthreads();
    const float scale = 0.125f;            // 1/sqrt(64)
    for (int j = tid; j <= s; j += 256) {
        const float* kr = k + ((size_t)(b * SS + j) * KVH + kvh) * HDIM;
        float d = 0.f;
#pragma unroll
        for (int x = 0; x < HDIM; x++) d = fmaf(qs[x], kr[x], d);
        sc[j] = d * scale;
    }
    __syncthreads();
    // max
    float m = -1e30f;
    for (int j = tid; j <= s; j += 256) m = fmaxf(m, sc[j]);
    for (int o2 = 32; o2 > 0; o2 >>= 1) m = fmaxf(m, __shfl_xor(m, o2, 64));
    if (lane == 0) redm[wid] = m;
    __syncthreads();
    m = fmaxf(fmaxf(redm[0], redm[1]), fmaxf(redm[2], redm[3]));
    // exp + sum
    float sum = 0.f;
    for (int j = tid; j <= s; j += 256) { float e = expf(sc[j] - m); sc[j] = e; sum += e; }
    for (int o2 = 32; o2 > 0; o2 >>= 1) sum += __shfl_xor(sum, o2, 64);
    if (lane == 0) reds[wid] = sum;
    __syncthreads();
    sum = reds[0] + reds[1] + reds[2] + reds[3];
    float inv = 1.f / sum;
    // PV: 4 waves split j, lane = head dim
    float accd = 0.f;
    for (int j = wid; j <= s; j += 4)
        accd = fmaf(sc[j], v[((size_t)(b * SS + j) * KVH + kvh) * HDIM + lane], accd);
    part[wid][lane] = accd;
    __syncthreads();
    if (wid == 0) {
        float r2 = (part[0][lane] + part[1][lane] + part[2][lane] + part[3][lane]) * inv;
        o[(size_t)t * HH * HDIM + h * HDIM + lane] = r2;
    }
}

// ---------------------------------------------------------------------------
// router: softmax over 8, top-2, normalize. Dense gates [T,E] (0 elsewhere).
__global__ void k_router(const float* __restrict__ logits, float* __restrict__ gates) {
    int t = blockIdx.x * 256 + threadIdx.x;
    if (t >= TT) return;
    const float* lg = logits + (size_t)t * EE;
    float mx = lg[0];
    for (int e = 1; e < EE; e++) mx = fmaxf(mx, lg[e]);
    float p[EE];
    for (int e = 0; e < EE; e++) p[e] = expf(lg[e] - mx);
    int i0 = 0;
    for (int e = 1; e < EE; e++) if (p[e] > p[i0]) i0 = e;
    int i1 = -1;
    for (int e = 0; e < EE; e++) {
        if (e == i0) continue;
        if (i1 < 0 || p[e] > p[i1]) i1 = e;
    }
    float w0 = p[i0], w1 = p[i1];
    float wsum = w0 + w1;
    float* gt = gates + (size_t)t * EE;
    for (int e = 0; e < EE; e++) gt[e] = 0.f;
    gt[i0] = w0 / wsum;
    gt[i1] = w1 / wsum;
}

// ---------------------------------------------------------------------------
__global__ void k_silu_mul(const float* __restrict__ g, const float* __restrict__ u,
                           float* __restrict__ out, int n) {
    int i = blockIdx.x * 256 + threadIdx.x;
    if (i < n) {
        float gv = g[i];
        out[i] = gv / (1.f + expf(-gv)) * u[i];
    }
}

// ---------------------------------------------------------------------------
extern "C" void kernel_launch(void* const* d_in, const int* in_sizes, int n_in,
                              void* d_out, int out_size, void* d_ws, size_t ws_size,
                              hipStream_t stream) {
    (void)in_sizes; (void)n_in; (void)out_size; (void)ws_size;
    const int*   token_ids    = (const int*)d_in[0];
    const int*   position_ids = (const int*)d_in[1];
    const float* tok_emb      = (const float*)d_in[2];
    const float* attn_norm_w  = (const float*)d_in[3];
    const float* wq           = (const float*)d_in[4];
    const float* wk           = (const float*)d_in[5];
    const float* wv           = (const float*)d_in[6];
    const float* q_norm_w     = (const float*)d_in[7];
    const float* k_norm_w     = (const float*)d_in[8];
    const float* wo           = (const float*)d_in[9];
    const float* ffn_norm_w   = (const float*)d_in[10];
    const float* router_w     = (const float*)d_in[11];
    const float* gate_w       = (const float*)d_in[12];
    const float* up_w         = (const float*)d_in[13];
    const float* down_w       = (const float*)d_in[14];
    const float* final_norm_w = (const float*)d_in[15];
    float* out = (float*)d_out;

    float* ws = (float*)d_ws;
    float* x    = ws;                       // [TT, DD]
    float* h    = x  + (size_t)TT * DD;     // [TT, DD]
    float* qb   = h  + (size_t)TT * DD;     // [TT, HH*HDIM]
    float* kb   = qb + (size_t)TT * DD;     // [TT, KVH*HDIM]
    float* vb   = kb + (size_t)TT * KVH * HDIM;
    float* ao   = vb + (size_t)TT * KVH * HDIM;  // [TT, DD]
    float* t1   = ao + (size_t)TT * DD;     // gate out [TT, FF]
    float* t2   = t1 + (size_t)TT * FF;     // up out
    float* t3   = t2 + (size_t)TT * FF;     // silu*up
    float* rl   = t3 + (size_t)TT * FF;     // router logits [TT, EE]
    float* gates= rl + (size_t)TT * EE;     // [TT, EE]

    dim3 blk2(16, 16);
    dim3 g_dd((DD + 63) / 64, (TT + 63) / 64);     // N=1024
    dim3 g_kv((KVH * HDIM + 63) / 64, (TT + 63) / 64); // N=256
    dim3 g_r(1, (TT + 63) / 64);                   // N=8
    dim3 g_lm((VV + 63) / 64, (TT + 63) / 64);     // N=32000

    k_embed<<<TT, 256, 0, stream>>>(token_ids, tok_emb, x);

    for (int l = 0; l < LL; l++) {
        const float* wq_l = wq + (size_t)l * DD * (HH * HDIM);
        const float* wk_l = wk + (size_t)l * DD * (KVH * HDIM);
        const float* wv_l = wv + (size_t)l * DD * (KVH * HDIM);
        const float* wo_l = wo + (size_t)l * (HH * HDIM) * DD;
        const float* rw_l = router_w + (size_t)l * DD * EE;

        k_rmsnorm<<<TT, 256, 0, stream>>>(x, attn_norm_w + (size_t)l * DD, h);
        k_gemm_nn<<<g_dd, blk2, 0, stream>>>(h, wq_l, qb, TT, HH * HDIM, DD, nullptr, 0, 0);
        k_gemm_nn<<<g_kv, blk2, 0, stream>>>(h, wk_l, kb, TT, KVH * HDIM, DD, nullptr, 0, 0);
        k_gemm_nn<<<g_kv, blk2, 0, stream>>>(h, wv_l, vb, TT, KVH * HDIM, DD, nullptr, 0, 0);
        k_qknorm_rope<<<(TT * HH) / 4, 256, 0, stream>>>(qb, q_norm_w + (size_t)l * HDIM,
                                                         position_ids, HH);
        k_qknorm_rope<<<(TT * KVH) / 4, 256, 0, stream>>>(kb, k_norm_w + (size_t)l * HDIM,
                                                          position_ids, KVH);
        k_attn<<<dim3(SS, BB * HH), 256, 0, stream>>>(qb, kb, vb, ao);
        // x += ao @ wo
        k_gemm_nn<<<g_dd, blk2, 0, stream>>>(ao, wo_l, x, TT, DD, HH * HDIM, nullptr, 0, 1);

        // MoE
        k_rmsnorm<<<TT, 256, 0, stream>>>(x, ffn_norm_w + (size_t)l * DD, h);
        k_gemm_nn<<<g_r, blk2, 0, stream>>>(h, rw_l, rl, TT, EE, DD, nullptr, 0, 0);
        k_router<<<(TT + 255) / 256, 256, 0, stream>>>(rl, gates);
        for (int e = 0; e < EE; e++) {
            const float* gw = gate_w + ((size_t)l * EE + e) * DD * FF;
            const float* uw = up_w   + ((size_t)l * EE + e) * DD * FF;
            const float* dw = down_w + ((size_t)l * EE + e) * FF * DD;
            k_gemm_nn<<<g_dd, blk2, 0, stream>>>(h, gw, t1, TT, FF, DD, nullptr, 0, 0);
            k_gemm_nn<<<g_dd, blk2, 0, stream>>>(h, uw, t2, TT, FF, DD, nullptr, 0, 0);
            int n = TT * FF;
            k_silu_mul<<<(n + 255) / 256, 256, 0, stream>>>(t1, t2, t3, n);
            // x += gates[:,e] * (t3 @ dw)
            k_gemm_nn<<<g_dd, blk2, 0, stream>>>(t3, dw, x, TT, DD, FF, gates + e, EE, 1);
        }
    }

    k_rmsnorm<<<TT, 256, 0, stream>>>(x, final_norm_w, h);
    k_gemm_nt<<<g_lm, blk2, 0, stream>>>(h, tok_emb, out, TT, VV, DD);
}